// Round 4
// baseline (1925.275 us; speedup 1.0000x reference)
//
#include <hip/hip_runtime.h>
#include <hip/hip_bf16.h>
#include <math.h>

#define EDIM 768
#define FDIM 2304
#define D1DIM 1536
#define SLEN 2048
#define BATCH 2
#define NHEAD 12
#define NTOK 4096

typedef __attribute__((ext_vector_type(8))) short bf16x8;
typedef __attribute__((ext_vector_type(4))) float f32x4;

__device__ __forceinline__ float sigmoidf_(float x) { return 1.0f / (1.0f + __expf(-x)); }

__device__ __forceinline__ unsigned short f2bf(float x) {
  __hip_bfloat16 h = __float2bfloat16(x);
  return *reinterpret_cast<unsigned short*>(&h);
}

// ---------------------------------------------------------------------------
// Stage a 64x64 fp32 tile (row stride ldk) into LDS as bf16, XOR-swizzled:
// row r (128 bytes) has 8 slots of 16B; slot' = slot ^ (r&7). Optional silu.
// 256 threads: thread t -> row t>>2, 16-col quarter t&3 (4x float4).
// ---------------------------------------------------------------------------
template <bool SILU>
__device__ __forceinline__ void stage64(const float* __restrict__ src, size_t ldk,
                                        short* dst, int tid) {
  int r = tid >> 2;
  int q = tid & 3;
  const float* row = src + (size_t)r * ldk + q * 16;
#pragma unroll
  for (int u = 0; u < 4; ++u) {
    float4 v = *reinterpret_cast<const float4*>(row + u * 4);
    if (SILU) {
      v.x *= sigmoidf_(v.x); v.y *= sigmoidf_(v.y);
      v.z *= sigmoidf_(v.z); v.w *= sigmoidf_(v.w);
    }
    int c0 = q * 16 + u * 4;
    int slot = c0 >> 3;
    int half = (c0 >> 2) & 1;
    int swz = slot ^ (r & 7);
    union { unsigned short us[4]; unsigned long long ull; } pk;
    pk.us[0] = f2bf(v.x); pk.us[1] = f2bf(v.y);
    pk.us[2] = f2bf(v.z); pk.us[3] = f2bf(v.w);
    *reinterpret_cast<unsigned long long*>(&dst[r * 64 + swz * 8 + half * 4]) = pk.ull;
  }
}

// ---------------------------------------------------------------------------
// One BK=64 MFMA stage: 4 waves in 2x2, each wave owns a 32x32 quadrant
// (2x2 fragments of 16x16), 2 K-steps of 32. Reads use the same XOR swizzle.
// A-frag/B-frag layout (gfx950 16x16x32 bf16): lane l holds row (l&15),
// k = (l>>4)*8 .. +7  -> one ds_read_b128 per fragment.
// ---------------------------------------------------------------------------
__device__ __forceinline__ void mma_stage(const short* As, const short* Ws,
                                          int wm, int wn, int lane,
                                          f32x4 (&acc)[2][2]) {
#pragma unroll
  for (int ks = 0; ks < 2; ++ks) {
    bf16x8 a[2], b[2];
#pragma unroll
    for (int f = 0; f < 2; ++f) {
      int ra = wm * 32 + f * 16 + (lane & 15);
      int sa = (ks * 4 + (lane >> 4)) ^ (ra & 7);
      a[f] = *reinterpret_cast<const bf16x8*>(&As[ra * 64 + sa * 8]);
      int rb = wn * 32 + f * 16 + (lane & 15);
      int sb = (ks * 4 + (lane >> 4)) ^ (rb & 7);
      b[f] = *reinterpret_cast<const bf16x8*>(&Ws[rb * 64 + sb * 8]);
    }
#pragma unroll
    for (int i = 0; i < 2; ++i)
#pragma unroll
      for (int j = 0; j < 2; ++j)
        acc[i][j] = __builtin_amdgcn_mfma_f32_16x16x32_bf16(a[i], b[j], acc[i][j], 0, 0, 0);
  }
}

// ---------------------------------------------------------------------------
// bf16-MFMA GEMM: C[n][o] = sum_k A[n][k]*W[o][k] + bias[o]. fp32 in/out,
// bf16 compute. 64x64 tile, BK=64. Grid (N/64, O/64), 256 threads.
// ---------------------------------------------------------------------------
__global__ __launch_bounds__(256) void gemm_mfma_bias(
    const float* __restrict__ A, const float* __restrict__ W,
    const float* __restrict__ bias, float* __restrict__ C, int K, int O) {
  __shared__ short As[64 * 64];
  __shared__ short Ws[64 * 64];
  int tid = threadIdx.x;
  int bm = blockIdx.x * 64, bo = blockIdx.y * 64;
  int lane = tid & 63, w = tid >> 6, wm = w >> 1, wn = w & 1;
  f32x4 acc[2][2];
#pragma unroll
  for (int i = 0; i < 2; ++i)
#pragma unroll
    for (int j = 0; j < 2; ++j)
#pragma unroll
      for (int e = 0; e < 4; ++e) acc[i][j][e] = 0.f;
  for (int kt = 0; kt < K; kt += 64) {
    stage64<false>(A + (size_t)bm * K + kt, K, As, tid);
    stage64<false>(W + (size_t)bo * K + kt, K, Ws, tid);
    __syncthreads();
    mma_stage(As, Ws, wm, wn, lane, acc);
    __syncthreads();
  }
#pragma unroll
  for (int i = 0; i < 2; ++i)
#pragma unroll
    for (int j = 0; j < 2; ++j) {
      int col = bo + wn * 32 + j * 16 + (lane & 15);
      float bv = bias[col];
#pragma unroll
      for (int r = 0; r < 4; ++r) {
        int row = bm + wm * 32 + i * 16 + (lane >> 4) * 4 + r;
        C[(size_t)row * O + col] = acc[i][j][r] + bv;
      }
    }
}

// ---------------------------------------------------------------------------
// KAN linear via bf16 MFMA, two accumulation phases into the same acc:
//  phase 1 (base):   A = silu(x)  (K = Kin),          W = bw[o][i]
//  phase 2 (spline): A = bases(x) (virtual K = Kin*8), W = sw[o][i][k]
//    virtual col = i*8+k is CONTIGUOUS in sw -> plain stage64 works.
//    A chunk: 8 inputs -> 64 cols; bases computed in fp32 in-register.
// ---------------------------------------------------------------------------
__global__ __launch_bounds__(256) void kan_mfma(
    const float* __restrict__ X, const float* __restrict__ bw,
    const float* __restrict__ sw, float* __restrict__ C, int Kin, int O) {
  __shared__ short As[64 * 64];
  __shared__ short Ws[64 * 64];
  int tid = threadIdx.x;
  int bm = blockIdx.x * 64, bo = blockIdx.y * 64;
  int lane = tid & 63, w = tid >> 6, wm = w >> 1, wn = w & 1;
  f32x4 acc[2][2];
#pragma unroll
  for (int i = 0; i < 2; ++i)
#pragma unroll
    for (int j = 0; j < 2; ++j)
#pragma unroll
      for (int e = 0; e < 4; ++e) acc[i][j][e] = 0.f;

  // phase 1: base (silu GEMM)
  for (int kt = 0; kt < Kin; kt += 64) {
    stage64<true>(X + (size_t)bm * Kin + kt, Kin, As, tid);
    stage64<false>(bw + (size_t)bo * Kin + kt, Kin, Ws, tid);
    __syncthreads();
    mma_stage(As, Ws, wm, wn, lane, acc);
    __syncthreads();
  }

  // phase 2: spline
  size_t ld2 = (size_t)Kin * 8;
  for (int ch = 0; ch < Kin / 8; ++ch) {
    // A: 64 rows x 8 inputs -> 8 cubic B-spline bases each (fp32 -> bf16)
#pragma unroll
    for (int u = 0; u < 2; ++u) {
      int p = tid + u * 256;
      int r = p >> 3, ii = p & 7;
      float x = X[(size_t)(bm + r) * Kin + ch * 8 + ii];
      // grid g(t) = (t-3)*0.4 - 1, t = 0..11; Cox-de Boor order 3
      float bb[11];
#pragma unroll
      for (int j = 0; j < 11; ++j) {
        float gj = (float)(j - 3) * 0.4f - 1.0f;
        float gj1 = (float)(j - 2) * 0.4f - 1.0f;
        bb[j] = (x >= gj && x < gj1) ? 1.0f : 0.0f;
      }
#pragma unroll
      for (int k = 1; k <= 3; ++k) {
        float inv = 1.0f / (0.4f * (float)k);
#pragma unroll
        for (int j = 0; j < 10; ++j) {
          if (j + k < 11) {
            float gj = (float)(j - 3) * 0.4f - 1.0f;
            float gk1 = (float)(j + k - 2) * 0.4f - 1.0f;  // g(j+k+1)
            bb[j] = (x - gj) * inv * bb[j] + (gk1 - x) * inv * bb[j + 1];
          }
        }
      }
      int swz = ii ^ (r & 7);
      union { unsigned short us[8]; unsigned long long ull[2]; } pk;
#pragma unroll
      for (int k2 = 0; k2 < 8; ++k2) pk.us[k2] = f2bf(bb[k2]);
      unsigned long long* d =
          reinterpret_cast<unsigned long long*>(&As[r * 64 + swz * 8]);
      d[0] = pk.ull[0];
      d[1] = pk.ull[1];
    }
    stage64<false>(sw + (size_t)bo * ld2 + ch * 64, ld2, Ws, tid);
    __syncthreads();
    mma_stage(As, Ws, wm, wn, lane, acc);
    __syncthreads();
  }

#pragma unroll
  for (int i = 0; i < 2; ++i)
#pragma unroll
    for (int j = 0; j < 2; ++j) {
      int col = bo + wn * 32 + j * 16 + (lane & 15);
#pragma unroll
      for (int r = 0; r < 4; ++r) {
        int row = bm + wm * 32 + i * 16 + (lane >> 4) * 4 + r;
        C[(size_t)row * O + col] = acc[i][j][r];
      }
    }
}

// ---------------------------------------------------------------------------
// Flash-style attention (fp32).
// qkv: (B*S, 2304), row = [q(12x64) k v]. One block = (b, head, 64 queries).
// ---------------------------------------------------------------------------
__global__ __launch_bounds__(256) void attn_kernel(const float* __restrict__ qkv,
                                                   float* __restrict__ ao) {
  __shared__ float Qs[64][65];
  __shared__ float Ks[64][65];
  __shared__ float Vs[64][64];
  __shared__ float Ps[64][67];
  __shared__ float mS[64], lS[64], cS[64];
  int tid = threadIdx.x;
  int qt = blockIdx.x, hd = blockIdx.y, b = blockIdx.z;
  for (int idx = tid; idx < 64 * 64; idx += 256) {
    int q = idx >> 6, d = idx & 63;
    Qs[q][d] = qkv[(size_t)(b * SLEN + qt * 64 + q) * FDIM + hd * 64 + d];
  }
  if (tid < 64) { mS[tid] = -1e30f; lS[tid] = 0.0f; }
  int q0 = (tid & 15) * 4;
  int x0 = (tid >> 4) * 4;
  float acc[4][4] = {};
  __syncthreads();
  for (int kt = 0; kt < SLEN / 64; ++kt) {
    for (int idx = tid; idx < 64 * 64; idx += 256) {
      int k = idx >> 6, d = idx & 63;
      size_t base = (size_t)(b * SLEN + kt * 64 + k) * FDIM + hd * 64 + d;
      Ks[k][d] = qkv[base + EDIM];
      Vs[k][d] = qkv[base + 2 * EDIM];
    }
    __syncthreads();
    {
      float s[4][4] = {};
      for (int d = 0; d < 64; ++d) {
        float qa[4], ka[4];
#pragma unroll
        for (int i = 0; i < 4; ++i) qa[i] = Qs[q0 + i][d];
#pragma unroll
        for (int j = 0; j < 4; ++j) ka[j] = Ks[x0 + j][d];
#pragma unroll
        for (int i = 0; i < 4; ++i)
#pragma unroll
          for (int j = 0; j < 4; ++j) s[i][j] += qa[i] * ka[j];
      }
#pragma unroll
      for (int i = 0; i < 4; ++i)
#pragma unroll
        for (int j = 0; j < 4; ++j) Ps[q0 + i][x0 + j] = s[i][j] * 0.125f;
    }
    __syncthreads();
    if (tid < 64) {
      float m_old = mS[tid], m = m_old;
#pragma unroll
      for (int k = 0; k < 64; ++k) m = fmaxf(m, Ps[tid][k]);
      float c = __expf(m_old - m);
      float l = lS[tid] * c;
#pragma unroll
      for (int k = 0; k < 64; ++k) {
        float p = __expf(Ps[tid][k] - m);
        Ps[tid][k] = p;
        l += p;
      }
      mS[tid] = m; lS[tid] = l; cS[tid] = c;
    }
    __syncthreads();
    {
      float cc[4];
#pragma unroll
      for (int i = 0; i < 4; ++i) cc[i] = cS[q0 + i];
#pragma unroll
      for (int i = 0; i < 4; ++i)
#pragma unroll
        for (int j = 0; j < 4; ++j) acc[i][j] *= cc[i];
      for (int k = 0; k < 64; ++k) {
        float p[4], v[4];
#pragma unroll
        for (int i = 0; i < 4; ++i) p[i] = Ps[q0 + i][k];
#pragma unroll
        for (int j = 0; j < 4; ++j) v[j] = Vs[k][x0 + j];
#pragma unroll
        for (int i = 0; i < 4; ++i)
#pragma unroll
          for (int j = 0; j < 4; ++j) acc[i][j] += p[i] * v[j];
      }
    }
    __syncthreads();
  }
#pragma unroll
  for (int i = 0; i < 4; ++i) {
    float invl = 1.0f / lS[q0 + i];
#pragma unroll
    for (int j = 0; j < 4; ++j)
      ao[(size_t)(b * SLEN + qt * 64 + q0 + i) * EDIM + hd * 64 + x0 + j] =
          acc[i][j] * invl;
  }
}

// ---------------------------------------------------------------------------
// Row-wise LayerNorm of (a+b), optional sigmoid(terrain) gate.
// ---------------------------------------------------------------------------
__global__ __launch_bounds__(256) void ln_kernel(
    const float* __restrict__ a, const float* __restrict__ b,
    const float* __restrict__ scale, const float* __restrict__ bias,
    const float* __restrict__ terrain, float* __restrict__ out) {
  int row = blockIdx.x;
  int tid = threadIdx.x;
  const float* pa = a + (size_t)row * EDIM;
  const float* pb = b + (size_t)row * EDIM;
  float v[3];
  float s = 0.f, ss = 0.f;
#pragma unroll
  for (int i = 0; i < 3; ++i) {
    float t = pa[tid + i * 256] + pb[tid + i * 256];
    v[i] = t; s += t; ss += t * t;
  }
#pragma unroll
  for (int off = 32; off > 0; off >>= 1) {
    s += __shfl_down(s, off);
    ss += __shfl_down(ss, off);
  }
  __shared__ float rs[4], rss[4];
  __shared__ float mu_s, rstd_s;
  int wv = tid >> 6;
  if ((tid & 63) == 0) { rs[wv] = s; rss[wv] = ss; }
  __syncthreads();
  if (tid == 0) {
    float S = rs[0] + rs[1] + rs[2] + rs[3];
    float SS = rss[0] + rss[1] + rss[2] + rss[3];
    float mu = S / (float)EDIM;
    float var = SS / (float)EDIM - mu * mu;
    mu_s = mu;
    rstd_s = rsqrtf(var + 1e-5f);
  }
  __syncthreads();
  float mu = mu_s, rstd = rstd_s;
  int bi = row / SLEN;
#pragma unroll
  for (int i = 0; i < 3; ++i) {
    int col = tid + i * 256;
    float y = (v[i] - mu) * rstd * scale[col] + bias[col];
    if (terrain) y *= sigmoidf_(terrain[bi * EDIM + col]);
    out[(size_t)row * EDIM + col] = y;
  }
}

// ---------------------------------------------------------------------------
// ws layout (floats), peak 62.9 MB with buffer reuse:
//   [0 .. 9.44M)   qkv (N x 2304) -> reuse: attn_out@0, h@3.15M, kan1@6.29M
//   [9.44M..12.6M) ao (N x 768)   -> reuse: kan0@9.44M (N x 1536)
// ---------------------------------------------------------------------------
extern "C" void kernel_launch(void* const* d_in, const int* in_sizes, int n_in,
                              void* d_out, int out_size, void* d_ws,
                              size_t ws_size, hipStream_t stream) {
  const float* x = (const float*)d_in[0];
  const float* terrain = (const float*)d_in[1];
  const float* qkv_w = (const float*)d_in[2];
  const float* qkv_b = (const float*)d_in[3];
  const float* out_w = (const float*)d_in[4];
  const float* out_b = (const float*)d_in[5];
  const float* ln1_s = (const float*)d_in[6];
  const float* ln1_b = (const float*)d_in[7];
  const float* bw0 = (const float*)d_in[8];
  const float* sw0 = (const float*)d_in[9];
  const float* bw1 = (const float*)d_in[10];
  const float* sw1 = (const float*)d_in[11];
  const float* ln2_s = (const float*)d_in[12];
  const float* ln2_b = (const float*)d_in[13];

  float* ws = (float*)d_ws;
  float* qkv = ws;                       // 4096*2304
  float* ao = ws + 9437184;              // 4096*768
  float* attn_out = ws;                  // reuse (qkv dead after attention)
  float* h = ws + 3145728;               // reuse
  float* kan0 = ws + 9437184;            // reuse (ao dead after out-proj)
  float* kan1 = ws + 6291456;            // reuse
  float* outp = (float*)d_out;

  // 1. qkv = x @ qkv_w^T + qkv_b        (4096 x 768 -> 2304)
  gemm_mfma_bias<<<dim3(64, 36), 256, 0, stream>>>(x, qkv_w, qkv_b, qkv, EDIM, FDIM);
  // 2. attention -> ao (4096 x 768)
  attn_kernel<<<dim3(SLEN / 64, NHEAD, BATCH), 256, 0, stream>>>(qkv, ao);
  // 3. attn_out = ao @ out_w^T + out_b  (4096 x 768 -> 768)
  gemm_mfma_bias<<<dim3(64, 12), 256, 0, stream>>>(ao, out_w, out_b, attn_out, EDIM, EDIM);
  // 4. h = LN(x + attn_out; ln1) * sigmoid(terrain)
  ln_kernel<<<NTOK, 256, 0, stream>>>(x, attn_out, ln1_s, ln1_b, terrain, h);
  // 5. kan0 = KAN(h; bw0, sw0)          (768 -> 1536)
  kan_mfma<<<dim3(64, 24), 256, 0, stream>>>(h, bw0, sw0, kan0, EDIM, D1DIM);
  // 6. kan1 = KAN(kan0; bw1, sw1)       (1536 -> 768)
  kan_mfma<<<dim3(64, 12), 256, 0, stream>>>(kan0, bw1, sw1, kan1, D1DIM, EDIM);
  // 7. out = LN(h + kan1; ln2)
  ln_kernel<<<NTOK, 256, 0, stream>>>(h, kan1, ln2_s, ln2_b, nullptr, outp);
}

// Round 5
// 1407.840 us; speedup vs baseline: 1.3675x; 1.3675x over previous
//
#include <hip/hip_runtime.h>
#include <hip/hip_bf16.h>
#include <math.h>

#define EDIM 768
#define FDIM 2304
#define D1DIM 1536
#define SLEN 2048
#define BATCH 2
#define NHEAD 12
#define NTOK 4096

typedef __attribute__((ext_vector_type(8))) short bf16x8;
typedef __attribute__((ext_vector_type(4))) float f32x4;

__device__ __forceinline__ float sigmoidf_(float x) { return 1.0f / (1.0f + __expf(-x)); }

__device__ __forceinline__ unsigned short f2bf(float x) {
  __hip_bfloat16 h = __float2bfloat16(x);
  return *reinterpret_cast<unsigned short*>(&h);
}

// ---------------------------------------------------------------------------
// Stage a 64x64 fp32 tile (row stride ldk) into LDS as bf16, XOR-swizzled:
// row r (128 bytes) has 8 slots of 16B; slot' = slot ^ (r&7). Optional silu.
// 256 threads: thread t -> row t>>2, 16-col quarter t&3 (4x float4).
// ---------------------------------------------------------------------------
template <bool SILU>
__device__ __forceinline__ void stage64(const float* __restrict__ src, size_t ldk,
                                        short* dst, int tid) {
  int r = tid >> 2;
  int q = tid & 3;
  const float* row = src + (size_t)r * ldk + q * 16;
#pragma unroll
  for (int u = 0; u < 4; ++u) {
    float4 v = *reinterpret_cast<const float4*>(row + u * 4);
    if (SILU) {
      v.x *= sigmoidf_(v.x); v.y *= sigmoidf_(v.y);
      v.z *= sigmoidf_(v.z); v.w *= sigmoidf_(v.w);
    }
    int c0 = q * 16 + u * 4;
    int slot = c0 >> 3;
    int half = (c0 >> 2) & 1;
    int swz = slot ^ (r & 7);
    union { unsigned short us[4]; unsigned long long ull; } pk;
    pk.us[0] = f2bf(v.x); pk.us[1] = f2bf(v.y);
    pk.us[2] = f2bf(v.z); pk.us[3] = f2bf(v.w);
    *reinterpret_cast<unsigned long long*>(&dst[r * 64 + swz * 8 + half * 4]) = pk.ull;
  }
}

// ---------------------------------------------------------------------------
// One BK=64 MFMA stage: 4 waves in 2x2, each wave owns a 32x32 quadrant
// (2x2 fragments of 16x16), 2 K-steps of 32. Reads use the same XOR swizzle.
// A-frag/B-frag layout (gfx950 16x16x32 bf16): lane l holds row (l&15),
// k = (l>>4)*8 .. +7  -> one ds_read_b128 per fragment.
// ---------------------------------------------------------------------------
__device__ __forceinline__ void mma_stage(const short* As, const short* Ws,
                                          int wm, int wn, int lane,
                                          f32x4 (&acc)[2][2]) {
#pragma unroll
  for (int ks = 0; ks < 2; ++ks) {
    bf16x8 a[2], b[2];
#pragma unroll
    for (int f = 0; f < 2; ++f) {
      int ra = wm * 32 + f * 16 + (lane & 15);
      int sa = (ks * 4 + (lane >> 4)) ^ (ra & 7);
      a[f] = *reinterpret_cast<const bf16x8*>(&As[ra * 64 + sa * 8]);
      int rb = wn * 32 + f * 16 + (lane & 15);
      int sb = (ks * 4 + (lane >> 4)) ^ (rb & 7);
      b[f] = *reinterpret_cast<const bf16x8*>(&Ws[rb * 64 + sb * 8]);
    }
#pragma unroll
    for (int i = 0; i < 2; ++i)
#pragma unroll
      for (int j = 0; j < 2; ++j)
        acc[i][j] = __builtin_amdgcn_mfma_f32_16x16x32_bf16(a[i], b[j], acc[i][j], 0, 0, 0);
  }
}

// ---------------------------------------------------------------------------
// bf16-MFMA GEMM: C[n][o] = sum_k A[n][k]*W[o][k] + bias[o]. fp32 in/out,
// bf16 compute. 64x64 tile, BK=64. Grid (N/64, O/64), 256 threads.
// ---------------------------------------------------------------------------
__global__ __launch_bounds__(256) void gemm_mfma_bias(
    const float* __restrict__ A, const float* __restrict__ W,
    const float* __restrict__ bias, float* __restrict__ C, int K, int O) {
  __shared__ short As[64 * 64];
  __shared__ short Ws[64 * 64];
  int tid = threadIdx.x;
  int bm = blockIdx.x * 64, bo = blockIdx.y * 64;
  int lane = tid & 63, w = tid >> 6, wm = w >> 1, wn = w & 1;
  f32x4 acc[2][2];
#pragma unroll
  for (int i = 0; i < 2; ++i)
#pragma unroll
    for (int j = 0; j < 2; ++j)
#pragma unroll
      for (int e = 0; e < 4; ++e) acc[i][j][e] = 0.f;
  for (int kt = 0; kt < K; kt += 64) {
    stage64<false>(A + (size_t)bm * K + kt, K, As, tid);
    stage64<false>(W + (size_t)bo * K + kt, K, Ws, tid);
    __syncthreads();
    mma_stage(As, Ws, wm, wn, lane, acc);
    __syncthreads();
  }
#pragma unroll
  for (int i = 0; i < 2; ++i)
#pragma unroll
    for (int j = 0; j < 2; ++j) {
      int col = bo + wn * 32 + j * 16 + (lane & 15);
      float bv = bias[col];
#pragma unroll
      for (int r = 0; r < 4; ++r) {
        int row = bm + wm * 32 + i * 16 + (lane >> 4) * 4 + r;
        C[(size_t)row * O + col] = acc[i][j][r] + bv;
      }
    }
}

// ---------------------------------------------------------------------------
// KAN linear via bf16 MFMA, two accumulation phases into the same acc:
//  phase 1 (base):   A = silu(x)  (K = Kin),          W = bw[o][i]
//  phase 2 (spline): A = bases(x) (virtual K = Kin*8), W = sw[o][i][k]
// ---------------------------------------------------------------------------
__global__ __launch_bounds__(256) void kan_mfma(
    const float* __restrict__ X, const float* __restrict__ bw,
    const float* __restrict__ sw, float* __restrict__ C, int Kin, int O) {
  __shared__ short As[64 * 64];
  __shared__ short Ws[64 * 64];
  int tid = threadIdx.x;
  int bm = blockIdx.x * 64, bo = blockIdx.y * 64;
  int lane = tid & 63, w = tid >> 6, wm = w >> 1, wn = w & 1;
  f32x4 acc[2][2];
#pragma unroll
  for (int i = 0; i < 2; ++i)
#pragma unroll
    for (int j = 0; j < 2; ++j)
#pragma unroll
      for (int e = 0; e < 4; ++e) acc[i][j][e] = 0.f;

  // phase 1: base (silu GEMM)
  for (int kt = 0; kt < Kin; kt += 64) {
    stage64<true>(X + (size_t)bm * Kin + kt, Kin, As, tid);
    stage64<false>(bw + (size_t)bo * Kin + kt, Kin, Ws, tid);
    __syncthreads();
    mma_stage(As, Ws, wm, wn, lane, acc);
    __syncthreads();
  }

  // phase 2: spline
  size_t ld2 = (size_t)Kin * 8;
  for (int ch = 0; ch < Kin / 8; ++ch) {
#pragma unroll
    for (int u = 0; u < 2; ++u) {
      int p = tid + u * 256;
      int r = p >> 3, ii = p & 7;
      float x = X[(size_t)(bm + r) * Kin + ch * 8 + ii];
      // grid g(t) = (t-3)*0.4 - 1, t = 0..11; Cox-de Boor order 3
      float bb[11];
#pragma unroll
      for (int j = 0; j < 11; ++j) {
        float gj = (float)(j - 3) * 0.4f - 1.0f;
        float gj1 = (float)(j - 2) * 0.4f - 1.0f;
        bb[j] = (x >= gj && x < gj1) ? 1.0f : 0.0f;
      }
#pragma unroll
      for (int k = 1; k <= 3; ++k) {
        float inv = 1.0f / (0.4f * (float)k);
#pragma unroll
        for (int j = 0; j < 10; ++j) {
          if (j + k < 11) {
            float gj = (float)(j - 3) * 0.4f - 1.0f;
            float gk1 = (float)(j + k - 2) * 0.4f - 1.0f;  // g(j+k+1)
            bb[j] = (x - gj) * inv * bb[j] + (gk1 - x) * inv * bb[j + 1];
          }
        }
      }
      int swz = ii ^ (r & 7);
      union { unsigned short us[8]; unsigned long long ull[2]; } pk;
#pragma unroll
      for (int k2 = 0; k2 < 8; ++k2) pk.us[k2] = f2bf(bb[k2]);
      unsigned long long* d =
          reinterpret_cast<unsigned long long*>(&As[r * 64 + swz * 8]);
      d[0] = pk.ull[0];
      d[1] = pk.ull[1];
    }
    stage64<false>(sw + (size_t)bo * ld2 + ch * 64, ld2, Ws, tid);
    __syncthreads();
    mma_stage(As, Ws, wm, wn, lane, acc);
    __syncthreads();
  }

#pragma unroll
  for (int i = 0; i < 2; ++i)
#pragma unroll
    for (int j = 0; j < 2; ++j) {
      int col = bo + wn * 32 + j * 16 + (lane & 15);
#pragma unroll
      for (int r = 0; r < 4; ++r) {
        int row = bm + wm * 32 + i * 16 + (lane >> 4) * 4 + r;
        C[(size_t)row * O + col] = acc[i][j][r];
      }
    }
}

// ---------------------------------------------------------------------------
// bf16-MFMA flash attention. qkv: (B*S, 2304), row = [q(12x64) k v].
// One block = (b, head, 64 queries), 256 threads (4 waves, 2x2).
// Per 64-key tile: stage K (coalesced) + V^T (4x4-block b64 writes) ->
// QK^T MFMA -> S fp32 LDS -> wave-parallel online softmax (4 lanes/row) ->
// P bf16 swizzled -> rescale + PV MFMA. Q pre-scaled by 1/8 (exact in bf16).
// ---------------------------------------------------------------------------
__global__ __launch_bounds__(256) void attn_mfma(const float* __restrict__ qkv,
                                                 float* __restrict__ ao) {
  __shared__ short Qs[64 * 64];
  __shared__ short Ks[64 * 64];
  __shared__ short Vt[64 * 64];
  __shared__ short Ps[64 * 64];
  __shared__ float Ss[64][65];
  __shared__ float mS[64], lS[64], cS[64];
  int tid = threadIdx.x;
  int qt = blockIdx.x, hd = blockIdx.y, b = blockIdx.z;
  int lane = tid & 63, w = tid >> 6, wm = w >> 1, wn = w & 1;

  // stage Q once, scaled by 1/8 (exponent shift: exact in bf16)
  {
    int r = tid >> 2, qq = tid & 3;
    const float* src = qkv + (size_t)(b * SLEN + qt * 64 + r) * FDIM + hd * 64 + qq * 16;
#pragma unroll
    for (int u = 0; u < 4; ++u) {
      float4 v = *reinterpret_cast<const float4*>(src + u * 4);
      int c0 = qq * 16 + u * 4;
      int swz = (c0 >> 3) ^ (r & 7);
      int half = (c0 >> 2) & 1;
      union { unsigned short us[4]; unsigned long long ull; } pk;
      pk.us[0] = f2bf(v.x * 0.125f); pk.us[1] = f2bf(v.y * 0.125f);
      pk.us[2] = f2bf(v.z * 0.125f); pk.us[3] = f2bf(v.w * 0.125f);
      *reinterpret_cast<unsigned long long*>(&Qs[r * 64 + swz * 8 + half * 4]) = pk.ull;
    }
  }
  if (tid < 64) { mS[tid] = -1e30f; lS[tid] = 0.0f; }
  f32x4 oacc[2][2];
#pragma unroll
  for (int i = 0; i < 2; ++i)
#pragma unroll
    for (int j = 0; j < 2; ++j)
#pragma unroll
      for (int e = 0; e < 4; ++e) oacc[i][j][e] = 0.f;
  __syncthreads();

  for (int kt = 0; kt < SLEN / 64; ++kt) {
    // stage K tile (coalesced, swizzled)
    stage64<false>(qkv + (size_t)(b * SLEN + kt * 64) * FDIM + EDIM + hd * 64,
                   FDIM, Ks, tid);
    // stage V transposed: thread owns 4x4 block (k = (tid&15)*4.., d = (tid>>4)*4..)
    {
      int kq = (tid & 15) * 4, dq = (tid >> 4) * 4;
      const float* vsrc =
          qkv + (size_t)(b * SLEN + kt * 64 + kq) * FDIM + 2 * EDIM + hd * 64 + dq;
      float4 vv[4];
#pragma unroll
      for (int i = 0; i < 4; ++i)
        vv[i] = *reinterpret_cast<const float4*>(vsrc + (size_t)i * FDIM);
      const float* vf = reinterpret_cast<const float*>(vv);
#pragma unroll
      for (int j = 0; j < 4; ++j) {
        int d = dq + j;
        union { unsigned short us[4]; unsigned long long ull; } pk;
#pragma unroll
        for (int i = 0; i < 4; ++i) pk.us[i] = f2bf(vf[i * 4 + j]);
        int slotp = (kq >> 3) ^ (d & 7);
        *reinterpret_cast<unsigned long long*>(&Vt[d * 64 + slotp * 8 + (kq & 7)]) =
            pk.ull;
      }
    }
    __syncthreads();

    // QK^T -> S (scores already scaled via Q)
    f32x4 s[2][2];
#pragma unroll
    for (int i = 0; i < 2; ++i)
#pragma unroll
      for (int j = 0; j < 2; ++j)
#pragma unroll
        for (int e = 0; e < 4; ++e) s[i][j][e] = 0.f;
    mma_stage(Qs, Ks, wm, wn, lane, s);
#pragma unroll
    for (int i = 0; i < 2; ++i)
#pragma unroll
      for (int j = 0; j < 2; ++j)
#pragma unroll
        for (int r = 0; r < 4; ++r)
          Ss[wm * 32 + i * 16 + (lane >> 4) * 4 + r][wn * 32 + j * 16 + (lane & 15)] =
              s[i][j][r];
    __syncthreads();

    // online softmax: 4 threads per row, 16 cols each
    {
      int row = tid >> 2, c0 = (tid & 3) * 16;
      float sv[16];
      float tm = -1e30f;
#pragma unroll
      for (int u = 0; u < 16; ++u) {
        sv[u] = Ss[row][c0 + u];
        tm = fmaxf(tm, sv[u]);
      }
      tm = fmaxf(tm, __shfl_xor(tm, 1));
      tm = fmaxf(tm, __shfl_xor(tm, 2));
      float m_old = mS[row];
      float m_new = fmaxf(m_old, tm);
      float c = __expf(m_old - m_new);
      float lsum = 0.f;
      union { unsigned short us[8]; bf16x8 v; } p0, p1;
#pragma unroll
      for (int u = 0; u < 8; ++u) {
        float p = __expf(sv[u] - m_new);
        lsum += p;
        p0.us[u] = f2bf(p);
      }
#pragma unroll
      for (int u = 0; u < 8; ++u) {
        float p = __expf(sv[8 + u] - m_new);
        lsum += p;
        p1.us[u] = f2bf(p);
      }
      lsum += __shfl_xor(lsum, 1);
      lsum += __shfl_xor(lsum, 2);
      int slot0 = (tid & 3) * 2;
      *reinterpret_cast<bf16x8*>(&Ps[row * 64 + (slot0 ^ (row & 7)) * 8]) = p0.v;
      *reinterpret_cast<bf16x8*>(&Ps[row * 64 + ((slot0 + 1) ^ (row & 7)) * 8]) = p1.v;
      if ((tid & 3) == 0) {
        lS[row] = lS[row] * c + lsum;
        mS[row] = m_new;
        cS[row] = c;
      }
    }
    __syncthreads();

    // rescale O by c, then accumulate P @ V
#pragma unroll
    for (int i = 0; i < 2; ++i)
#pragma unroll
      for (int r = 0; r < 4; ++r) {
        float cr = cS[wm * 32 + i * 16 + (lane >> 4) * 4 + r];
#pragma unroll
        for (int j = 0; j < 2; ++j) oacc[i][j][r] *= cr;
      }
    mma_stage(Ps, Vt, wm, wn, lane, oacc);
    __syncthreads();
  }

  // epilogue: divide by l, write ao
#pragma unroll
  for (int i = 0; i < 2; ++i)
#pragma unroll
    for (int r = 0; r < 4; ++r) {
      int row = wm * 32 + i * 16 + (lane >> 4) * 4 + r;
      float invl = 1.0f / lS[row];
#pragma unroll
      for (int j = 0; j < 2; ++j) {
        int col = wn * 32 + j * 16 + (lane & 15);
        ao[(size_t)(b * SLEN + qt * 64 + row) * EDIM + hd * 64 + col] =
            oacc[i][j][r] * invl;
      }
    }
}

// ---------------------------------------------------------------------------
// Row-wise LayerNorm of (a+b), optional sigmoid(terrain) gate.
// ---------------------------------------------------------------------------
__global__ __launch_bounds__(256) void ln_kernel(
    const float* __restrict__ a, const float* __restrict__ b,
    const float* __restrict__ scale, const float* __restrict__ bias,
    const float* __restrict__ terrain, float* __restrict__ out) {
  int row = blockIdx.x;
  int tid = threadIdx.x;
  const float* pa = a + (size_t)row * EDIM;
  const float* pb = b + (size_t)row * EDIM;
  float v[3];
  float s = 0.f, ss = 0.f;
#pragma unroll
  for (int i = 0; i < 3; ++i) {
    float t = pa[tid + i * 256] + pb[tid + i * 256];
    v[i] = t; s += t; ss += t * t;
  }
#pragma unroll
  for (int off = 32; off > 0; off >>= 1) {
    s += __shfl_down(s, off);
    ss += __shfl_down(ss, off);
  }
  __shared__ float rs[4], rss[4];
  __shared__ float mu_s, rstd_s;
  int wv = tid >> 6;
  if ((tid & 63) == 0) { rs[wv] = s; rss[wv] = ss; }
  __syncthreads();
  if (tid == 0) {
    float S = rs[0] + rs[1] + rs[2] + rs[3];
    float SS = rss[0] + rss[1] + rss[2] + rss[3];
    float mu = S / (float)EDIM;
    float var = SS / (float)EDIM - mu * mu;
    mu_s = mu;
    rstd_s = rsqrtf(var + 1e-5f);
  }
  __syncthreads();
  float mu = mu_s, rstd = rstd_s;
  int bi = row / SLEN;
#pragma unroll
  for (int i = 0; i < 3; ++i) {
    int col = tid + i * 256;
    float y = (v[i] - mu) * rstd * scale[col] + bias[col];
    if (terrain) y *= sigmoidf_(terrain[bi * EDIM + col]);
    out[(size_t)row * EDIM + col] = y;
  }
}

// ---------------------------------------------------------------------------
// ws layout (floats), peak 62.9 MB with buffer reuse:
//   [0 .. 9.44M)   qkv (N x 2304) -> reuse: attn_out@0, h@3.15M, kan1@6.29M
//   [9.44M..12.6M) ao (N x 768)   -> reuse: kan0@9.44M (N x 1536)
// ---------------------------------------------------------------------------
extern "C" void kernel_launch(void* const* d_in, const int* in_sizes, int n_in,
                              void* d_out, int out_size, void* d_ws,
                              size_t ws_size, hipStream_t stream) {
  const float* x = (const float*)d_in[0];
  const float* terrain = (const float*)d_in[1];
  const float* qkv_w = (const float*)d_in[2];
  const float* qkv_b = (const float*)d_in[3];
  const float* out_w = (const float*)d_in[4];
  const float* out_b = (const float*)d_in[5];
  const float* ln1_s = (const float*)d_in[6];
  const float* ln1_b = (const float*)d_in[7];
  const float* bw0 = (const float*)d_in[8];
  const float* sw0 = (const float*)d_in[9];
  const float* bw1 = (const float*)d_in[10];
  const float* sw1 = (const float*)d_in[11];
  const float* ln2_s = (const float*)d_in[12];
  const float* ln2_b = (const float*)d_in[13];

  float* ws = (float*)d_ws;
  float* qkv = ws;                       // 4096*2304
  float* ao = ws + 9437184;              // 4096*768
  float* attn_out = ws;                  // reuse (qkv dead after attention)
  float* h = ws + 3145728;               // reuse
  float* kan0 = ws + 9437184;            // reuse (ao dead after out-proj)
  float* kan1 = ws + 6291456;            // reuse
  float* outp = (float*)d_out;

  // 1. qkv = x @ qkv_w^T + qkv_b        (4096 x 768 -> 2304)
  gemm_mfma_bias<<<dim3(64, 36), 256, 0, stream>>>(x, qkv_w, qkv_b, qkv, EDIM, FDIM);
  // 2. attention -> ao (4096 x 768)
  attn_mfma<<<dim3(SLEN / 64, NHEAD, BATCH), 256, 0, stream>>>(qkv, ao);
  // 3. attn_out = ao @ out_w^T + out_b  (4096 x 768 -> 768)
  gemm_mfma_bias<<<dim3(64, 12), 256, 0, stream>>>(ao, out_w, out_b, attn_out, EDIM, EDIM);
  // 4. h = LN(x + attn_out; ln1) * sigmoid(terrain)
  ln_kernel<<<NTOK, 256, 0, stream>>>(x, attn_out, ln1_s, ln1_b, terrain, h);
  // 5. kan0 = KAN(h; bw0, sw0)          (768 -> 1536)
  kan_mfma<<<dim3(64, 24), 256, 0, stream>>>(h, bw0, sw0, kan0, EDIM, D1DIM);
  // 6. kan1 = KAN(kan0; bw1, sw1)       (1536 -> 768)
  kan_mfma<<<dim3(64, 12), 256, 0, stream>>>(kan0, bw1, sw1, kan1, D1DIM, EDIM);
  // 7. out = LN(h + kan1; ln2)
  ln_kernel<<<NTOK, 256, 0, stream>>>(h, kan1, ln2_s, ln2_b, nullptr, outp);
}

// Round 6
// 924.498 us; speedup vs baseline: 2.0825x; 1.5228x over previous
//
#include <hip/hip_runtime.h>
#include <hip/hip_bf16.h>
#include <math.h>

#define EDIM 768
#define FDIM 2304
#define D1DIM 1536
#define SLEN 2048
#define BATCH 2
#define NHEAD 12
#define NTOK 4096

typedef __attribute__((ext_vector_type(8))) short bf16x8;
typedef __attribute__((ext_vector_type(4))) float f32x4;

__device__ __forceinline__ float sigmoidf_(float x) { return 1.0f / (1.0f + __expf(-x)); }

__device__ __forceinline__ unsigned short f2bf(float x) {
  __hip_bfloat16 h = __float2bfloat16(x);
  return *reinterpret_cast<unsigned short*>(&h);
}

// Cubic B-spline bases on grid g(t) = (t-3)*0.4 - 1, t = 0..11 (Cox-de Boor),
// returns the 8 order-3 bases in bb[0..7].
__device__ __forceinline__ void bspline8(float x, float* bb /*[11]*/) {
#pragma unroll
  for (int j = 0; j < 11; ++j) {
    float gj = (float)(j - 3) * 0.4f - 1.0f;
    float gj1 = (float)(j - 2) * 0.4f - 1.0f;
    bb[j] = (x >= gj && x < gj1) ? 1.0f : 0.0f;
  }
#pragma unroll
  for (int k = 1; k <= 3; ++k) {
    float inv = 1.0f / (0.4f * (float)k);
#pragma unroll
    for (int j = 0; j < 10; ++j) {
      if (j + k < 11) {
        float gj = (float)(j - 3) * 0.4f - 1.0f;
        float gk1 = (float)(j + k - 2) * 0.4f - 1.0f;  // g(j+k+1)
        bb[j] = (x - gj) * inv * bb[j] + (gk1 - x) * inv * bb[j + 1];
      }
    }
  }
}

// ---------------------------------------------------------------------------
// Stage a 64x64 fp32 tile (row stride ldk) into LDS as bf16, XOR-swizzled:
// row r (128 bytes) has 8 slots of 16B; slot' = slot ^ (r&7). Optional silu.
// ---------------------------------------------------------------------------
template <bool SILU>
__device__ __forceinline__ void stage64(const float* __restrict__ src, size_t ldk,
                                        short* dst, int tid) {
  int r = tid >> 2;
  int q = tid & 3;
  const float* row = src + (size_t)r * ldk + q * 16;
#pragma unroll
  for (int u = 0; u < 4; ++u) {
    float4 v = *reinterpret_cast<const float4*>(row + u * 4);
    if (SILU) {
      v.x *= sigmoidf_(v.x); v.y *= sigmoidf_(v.y);
      v.z *= sigmoidf_(v.z); v.w *= sigmoidf_(v.w);
    }
    int c0 = q * 16 + u * 4;
    int slot = c0 >> 3;
    int half = (c0 >> 2) & 1;
    int swz = slot ^ (r & 7);
    union { unsigned short us[4]; unsigned long long ull; } pk;
    pk.us[0] = f2bf(v.x); pk.us[1] = f2bf(v.y);
    pk.us[2] = f2bf(v.z); pk.us[3] = f2bf(v.w);
    *reinterpret_cast<unsigned long long*>(&dst[r * 64 + swz * 8 + half * 4]) = pk.ull;
  }
}

// Same, but source already bf16 (pure copy into swizzled layout).
__device__ __forceinline__ void stage64bf(const unsigned short* __restrict__ src,
                                          size_t ldk, short* dst, int tid) {
  int r = tid >> 2;
  int q = tid & 3;
  const unsigned short* row = src + (size_t)r * ldk + q * 16;
  bf16x8 v0 = *reinterpret_cast<const bf16x8*>(row);
  bf16x8 v1 = *reinterpret_cast<const bf16x8*>(row + 8);
  int s0 = (q * 2) ^ (r & 7);
  int s1 = (q * 2 + 1) ^ (r & 7);
  *reinterpret_cast<bf16x8*>(&dst[r * 64 + s0 * 8]) = v0;
  *reinterpret_cast<bf16x8*>(&dst[r * 64 + s1 * 8]) = v1;
}

// ---------------------------------------------------------------------------
// One BK=64 MFMA stage: 4 waves in 2x2, each wave owns a 32x32 quadrant
// (2x2 fragments of 16x16), 2 K-steps of 32. Reads invert the XOR swizzle.
// ---------------------------------------------------------------------------
__device__ __forceinline__ void mma_stage(const short* As, const short* Ws,
                                          int wm, int wn, int lane,
                                          f32x4 (&acc)[2][2]) {
#pragma unroll
  for (int ks = 0; ks < 2; ++ks) {
    bf16x8 a[2], b[2];
#pragma unroll
    for (int f = 0; f < 2; ++f) {
      int ra = wm * 32 + f * 16 + (lane & 15);
      int sa = (ks * 4 + (lane >> 4)) ^ (ra & 7);
      a[f] = *reinterpret_cast<const bf16x8*>(&As[ra * 64 + sa * 8]);
      int rb = wn * 32 + f * 16 + (lane & 15);
      int sb = (ks * 4 + (lane >> 4)) ^ (rb & 7);
      b[f] = *reinterpret_cast<const bf16x8*>(&Ws[rb * 64 + sb * 8]);
    }
#pragma unroll
    for (int i = 0; i < 2; ++i)
#pragma unroll
      for (int j = 0; j < 2; ++j)
        acc[i][j] = __builtin_amdgcn_mfma_f32_16x16x32_bf16(a[i], b[j], acc[i][j], 0, 0, 0);
  }
}

// ---------------------------------------------------------------------------
// bf16-MFMA GEMM: C[n][o] = sum_k A[n][k]*W[o][k] + bias[o]. fp32 in/out.
// ---------------------------------------------------------------------------
__global__ __launch_bounds__(256) void gemm_mfma_bias(
    const float* __restrict__ A, const float* __restrict__ W,
    const float* __restrict__ bias, float* __restrict__ C, int K, int O) {
  __shared__ short As[64 * 64];
  __shared__ short Ws[64 * 64];
  int tid = threadIdx.x;
  int bm = blockIdx.x * 64, bo = blockIdx.y * 64;
  int lane = tid & 63, w = tid >> 6, wm = w >> 1, wn = w & 1;
  f32x4 acc[2][2];
#pragma unroll
  for (int i = 0; i < 2; ++i)
#pragma unroll
    for (int j = 0; j < 2; ++j)
#pragma unroll
      for (int e = 0; e < 4; ++e) acc[i][j][e] = 0.f;
  for (int kt = 0; kt < K; kt += 64) {
    stage64<false>(A + (size_t)bm * K + kt, K, As, tid);
    stage64<false>(W + (size_t)bo * K + kt, K, Ws, tid);
    __syncthreads();
    mma_stage(As, Ws, wm, wn, lane, acc);
    __syncthreads();
  }
#pragma unroll
  for (int i = 0; i < 2; ++i)
#pragma unroll
    for (int j = 0; j < 2; ++j) {
      int col = bo + wn * 32 + j * 16 + (lane & 15);
      float bv = bias[col];
#pragma unroll
      for (int r = 0; r < 4; ++r) {
        int row = bm + wm * 32 + i * 16 + (lane >> 4) * 4 + r;
        C[(size_t)row * O + col] = acc[i][j][r] + bv;
      }
    }
}

// ---------------------------------------------------------------------------
// KAN prep: per element x[n][i] write silu(x) -> Abase[n][i] (bf16) and the
// 8 cubic B-spline bases -> Aspl[n][i*8..] (bf16, one 16B store).
// Grid-stride, one element per thread-step.
// ---------------------------------------------------------------------------
__global__ __launch_bounds__(256) void kan_prep(
    const float* __restrict__ X, unsigned short* __restrict__ Abase,
    unsigned short* __restrict__ Aspl, int total) {
  for (int idx = blockIdx.x * 256 + threadIdx.x; idx < total;
       idx += gridDim.x * 256) {
    float x = X[idx];
    Abase[idx] = f2bf(x * sigmoidf_(x));
    float bb[11];
    bspline8(x, bb);
    union { unsigned short us[8]; bf16x8 v; } pk;
#pragma unroll
    for (int k = 0; k < 8; ++k) pk.us[k] = f2bf(bb[k]);
    *reinterpret_cast<bf16x8*>(&Aspl[(size_t)idx * 8]) = pk.v;
  }
}

// ---------------------------------------------------------------------------
// KAN GEMM with precomputed bf16 A: two phases accumulate into one acc:
//  phase 1: A = Abase (N x Kin),    W = bw[o][i]   (fp32 -> bf16 staged)
//  phase 2: A = Aspl  (N x Kin*8),  W = sw[o][i][k]
// ---------------------------------------------------------------------------
__global__ __launch_bounds__(256) void kan_gemm_pre(
    const unsigned short* __restrict__ Abase, const unsigned short* __restrict__ Aspl,
    const float* __restrict__ bw, const float* __restrict__ sw,
    float* __restrict__ C, int Kin, int O) {
  __shared__ short As[64 * 64];
  __shared__ short Ws[64 * 64];
  int tid = threadIdx.x;
  int bm = blockIdx.x * 64, bo = blockIdx.y * 64;
  int lane = tid & 63, w = tid >> 6, wm = w >> 1, wn = w & 1;
  f32x4 acc[2][2];
#pragma unroll
  for (int i = 0; i < 2; ++i)
#pragma unroll
    for (int j = 0; j < 2; ++j)
#pragma unroll
      for (int e = 0; e < 4; ++e) acc[i][j][e] = 0.f;

  // phase 1: base
  for (int kt = 0; kt < Kin; kt += 64) {
    stage64bf(Abase + (size_t)bm * Kin + kt, Kin, As, tid);
    stage64<false>(bw + (size_t)bo * Kin + kt, Kin, Ws, tid);
    __syncthreads();
    mma_stage(As, Ws, wm, wn, lane, acc);
    __syncthreads();
  }
  // phase 2: spline
  size_t ld2 = (size_t)Kin * 8;
  for (int kt = 0; kt < (int)ld2; kt += 64) {
    stage64bf(Aspl + (size_t)bm * ld2 + kt, ld2, As, tid);
    stage64<false>(sw + (size_t)bo * ld2 + kt, ld2, Ws, tid);
    __syncthreads();
    mma_stage(As, Ws, wm, wn, lane, acc);
    __syncthreads();
  }

#pragma unroll
  for (int i = 0; i < 2; ++i)
#pragma unroll
    for (int j = 0; j < 2; ++j) {
      int col = bo + wn * 32 + j * 16 + (lane & 15);
#pragma unroll
      for (int r = 0; r < 4; ++r) {
        int row = bm + wm * 32 + i * 16 + (lane >> 4) * 4 + r;
        C[(size_t)row * O + col] = acc[i][j][r];
      }
    }
}

// ---------------------------------------------------------------------------
// Fallback KAN (in-GEMM recompute) for small ws_size — round-4-verified.
// ---------------------------------------------------------------------------
__global__ __launch_bounds__(256) void kan_mfma(
    const float* __restrict__ X, const float* __restrict__ bw,
    const float* __restrict__ sw, float* __restrict__ C, int Kin, int O) {
  __shared__ short As[64 * 64];
  __shared__ short Ws[64 * 64];
  int tid = threadIdx.x;
  int bm = blockIdx.x * 64, bo = blockIdx.y * 64;
  int lane = tid & 63, w = tid >> 6, wm = w >> 1, wn = w & 1;
  f32x4 acc[2][2];
#pragma unroll
  for (int i = 0; i < 2; ++i)
#pragma unroll
    for (int j = 0; j < 2; ++j)
#pragma unroll
      for (int e = 0; e < 4; ++e) acc[i][j][e] = 0.f;
  for (int kt = 0; kt < Kin; kt += 64) {
    stage64<true>(X + (size_t)bm * Kin + kt, Kin, As, tid);
    stage64<false>(bw + (size_t)bo * Kin + kt, Kin, Ws, tid);
    __syncthreads();
    mma_stage(As, Ws, wm, wn, lane, acc);
    __syncthreads();
  }
  size_t ld2 = (size_t)Kin * 8;
  for (int ch = 0; ch < Kin / 8; ++ch) {
#pragma unroll
    for (int u = 0; u < 2; ++u) {
      int p = tid + u * 256;
      int r = p >> 3, ii = p & 7;
      float x = X[(size_t)(bm + r) * Kin + ch * 8 + ii];
      float bb[11];
      bspline8(x, bb);
      int swz = ii ^ (r & 7);
      union { unsigned short us[8]; unsigned long long ull[2]; } pk;
#pragma unroll
      for (int k2 = 0; k2 < 8; ++k2) pk.us[k2] = f2bf(bb[k2]);
      unsigned long long* d =
          reinterpret_cast<unsigned long long*>(&As[r * 64 + swz * 8]);
      d[0] = pk.ull[0];
      d[1] = pk.ull[1];
    }
    stage64<false>(sw + (size_t)bo * ld2 + ch * 64, ld2, Ws, tid);
    __syncthreads();
    mma_stage(As, Ws, wm, wn, lane, acc);
    __syncthreads();
  }
#pragma unroll
  for (int i = 0; i < 2; ++i)
#pragma unroll
    for (int j = 0; j < 2; ++j) {
      int col = bo + wn * 32 + j * 16 + (lane & 15);
#pragma unroll
      for (int r = 0; r < 4; ++r) {
        int row = bm + wm * 32 + i * 16 + (lane >> 4) * 4 + r;
        C[(size_t)row * O + col] = acc[i][j][r];
      }
    }
}

// ---------------------------------------------------------------------------
// bf16-MFMA flash attention (round-5-verified).
// ---------------------------------------------------------------------------
__global__ __launch_bounds__(256) void attn_mfma(const float* __restrict__ qkv,
                                                 float* __restrict__ ao) {
  __shared__ short Qs[64 * 64];
  __shared__ short Ks[64 * 64];
  __shared__ short Vt[64 * 64];
  __shared__ short Ps[64 * 64];
  __shared__ float Ss[64][65];
  __shared__ float mS[64], lS[64], cS[64];
  int tid = threadIdx.x;
  int qt = blockIdx.x, hd = blockIdx.y, b = blockIdx.z;
  int lane = tid & 63, w = tid >> 6, wm = w >> 1, wn = w & 1;

  {
    int r = tid >> 2, qq = tid & 3;
    const float* src = qkv + (size_t)(b * SLEN + qt * 64 + r) * FDIM + hd * 64 + qq * 16;
#pragma unroll
    for (int u = 0; u < 4; ++u) {
      float4 v = *reinterpret_cast<const float4*>(src + u * 4);
      int c0 = qq * 16 + u * 4;
      int swz = (c0 >> 3) ^ (r & 7);
      int half = (c0 >> 2) & 1;
      union { unsigned short us[4]; unsigned long long ull; } pk;
      pk.us[0] = f2bf(v.x * 0.125f); pk.us[1] = f2bf(v.y * 0.125f);
      pk.us[2] = f2bf(v.z * 0.125f); pk.us[3] = f2bf(v.w * 0.125f);
      *reinterpret_cast<unsigned long long*>(&Qs[r * 64 + swz * 8 + half * 4]) = pk.ull;
    }
  }
  if (tid < 64) { mS[tid] = -1e30f; lS[tid] = 0.0f; }
  f32x4 oacc[2][2];
#pragma unroll
  for (int i = 0; i < 2; ++i)
#pragma unroll
    for (int j = 0; j < 2; ++j)
#pragma unroll
      for (int e = 0; e < 4; ++e) oacc[i][j][e] = 0.f;
  __syncthreads();

  for (int kt = 0; kt < SLEN / 64; ++kt) {
    stage64<false>(qkv + (size_t)(b * SLEN + kt * 64) * FDIM + EDIM + hd * 64,
                   FDIM, Ks, tid);
    {
      int kq = (tid & 15) * 4, dq = (tid >> 4) * 4;
      const float* vsrc =
          qkv + (size_t)(b * SLEN + kt * 64 + kq) * FDIM + 2 * EDIM + hd * 64 + dq;
      float4 vv[4];
#pragma unroll
      for (int i = 0; i < 4; ++i)
        vv[i] = *reinterpret_cast<const float4*>(vsrc + (size_t)i * FDIM);
      const float* vf = reinterpret_cast<const float*>(vv);
#pragma unroll
      for (int j = 0; j < 4; ++j) {
        int d = dq + j;
        union { unsigned short us[4]; unsigned long long ull; } pk;
#pragma unroll
        for (int i = 0; i < 4; ++i) pk.us[i] = f2bf(vf[i * 4 + j]);
        int slotp = (kq >> 3) ^ (d & 7);
        *reinterpret_cast<unsigned long long*>(&Vt[d * 64 + slotp * 8 + (kq & 7)]) =
            pk.ull;
      }
    }
    __syncthreads();

    f32x4 s[2][2];
#pragma unroll
    for (int i = 0; i < 2; ++i)
#pragma unroll
      for (int j = 0; j < 2; ++j)
#pragma unroll
        for (int e = 0; e < 4; ++e) s[i][j][e] = 0.f;
    mma_stage(Qs, Ks, wm, wn, lane, s);
#pragma unroll
    for (int i = 0; i < 2; ++i)
#pragma unroll
      for (int j = 0; j < 2; ++j)
#pragma unroll
        for (int r = 0; r < 4; ++r)
          Ss[wm * 32 + i * 16 + (lane >> 4) * 4 + r][wn * 32 + j * 16 + (lane & 15)] =
              s[i][j][r];
    __syncthreads();

    {
      int row = tid >> 2, c0 = (tid & 3) * 16;
      float sv[16];
      float tm = -1e30f;
#pragma unroll
      for (int u = 0; u < 16; ++u) {
        sv[u] = Ss[row][c0 + u];
        tm = fmaxf(tm, sv[u]);
      }
      tm = fmaxf(tm, __shfl_xor(tm, 1));
      tm = fmaxf(tm, __shfl_xor(tm, 2));
      float m_old = mS[row];
      float m_new = fmaxf(m_old, tm);
      float c = __expf(m_old - m_new);
      float lsum = 0.f;
      union { unsigned short us[8]; bf16x8 v; } p0, p1;
#pragma unroll
      for (int u = 0; u < 8; ++u) {
        float p = __expf(sv[u] - m_new);
        lsum += p;
        p0.us[u] = f2bf(p);
      }
#pragma unroll
      for (int u = 0; u < 8; ++u) {
        float p = __expf(sv[8 + u] - m_new);
        lsum += p;
        p1.us[u] = f2bf(p);
      }
      lsum += __shfl_xor(lsum, 1);
      lsum += __shfl_xor(lsum, 2);
      int slot0 = (tid & 3) * 2;
      *reinterpret_cast<bf16x8*>(&Ps[row * 64 + (slot0 ^ (row & 7)) * 8]) = p0.v;
      *reinterpret_cast<bf16x8*>(&Ps[row * 64 + ((slot0 + 1) ^ (row & 7)) * 8]) = p1.v;
      if ((tid & 3) == 0) {
        lS[row] = lS[row] * c + lsum;
        mS[row] = m_new;
        cS[row] = c;
      }
    }
    __syncthreads();

#pragma unroll
    for (int i = 0; i < 2; ++i)
#pragma unroll
      for (int r = 0; r < 4; ++r) {
        float cr = cS[wm * 32 + i * 16 + (lane >> 4) * 4 + r];
#pragma unroll
        for (int j = 0; j < 2; ++j) oacc[i][j][r] *= cr;
      }
    mma_stage(Ps, Vt, wm, wn, lane, oacc);
    __syncthreads();
  }

#pragma unroll
  for (int i = 0; i < 2; ++i)
#pragma unroll
    for (int r = 0; r < 4; ++r) {
      int row = wm * 32 + i * 16 + (lane >> 4) * 4 + r;
      float invl = 1.0f / lS[row];
#pragma unroll
      for (int j = 0; j < 2; ++j) {
        int col = wn * 32 + j * 16 + (lane & 15);
        ao[(size_t)(b * SLEN + qt * 64 + row) * EDIM + hd * 64 + col] =
            oacc[i][j][r] * invl;
      }
    }
}

// ---------------------------------------------------------------------------
// Row-wise LayerNorm of (a+b), optional sigmoid(terrain) gate.
// ---------------------------------------------------------------------------
__global__ __launch_bounds__(256) void ln_kernel(
    const float* __restrict__ a, const float* __restrict__ b,
    const float* __restrict__ scale, const float* __restrict__ bias,
    const float* __restrict__ terrain, float* __restrict__ out) {
  int row = blockIdx.x;
  int tid = threadIdx.x;
  const float* pa = a + (size_t)row * EDIM;
  const float* pb = b + (size_t)row * EDIM;
  float v[3];
  float s = 0.f, ss = 0.f;
#pragma unroll
  for (int i = 0; i < 3; ++i) {
    float t = pa[tid + i * 256] + pb[tid + i * 256];
    v[i] = t; s += t; ss += t * t;
  }
#pragma unroll
  for (int off = 32; off > 0; off >>= 1) {
    s += __shfl_down(s, off);
    ss += __shfl_down(ss, off);
  }
  __shared__ float rs[4], rss[4];
  __shared__ float mu_s, rstd_s;
  int wv = tid >> 6;
  if ((tid & 63) == 0) { rs[wv] = s; rss[wv] = ss; }
  __syncthreads();
  if (tid == 0) {
    float S = rs[0] + rs[1] + rs[2] + rs[3];
    float SS = rss[0] + rss[1] + rss[2] + rss[3];
    float mu = S / (float)EDIM;
    float var = SS / (float)EDIM - mu * mu;
    mu_s = mu;
    rstd_s = rsqrtf(var + 1e-5f);
  }
  __syncthreads();
  float mu = mu_s, rstd = rstd_s;
  int bi = row / SLEN;
#pragma unroll
  for (int i = 0; i < 3; ++i) {
    int col = tid + i * 256;
    float y = (v[i] - mu) * rstd * scale[col] + bias[col];
    if (terrain) y *= sigmoidf_(terrain[bi * EDIM + col]);
    out[(size_t)row * EDIM + col] = y;
  }
}

// ---------------------------------------------------------------------------
// ws layout (bytes):
//   [0 .. 62,914,560)  fp32 region (as before):
//     qkv@0 (37.7MB) -> reuse attn_out@0, h@12.6MB, kan1@25.2MB
//     ao@37.7MB      -> reuse kan0@37.7MB (25.2MB)
//   [62,914,560 .. 176,160,768)  bf16 A region (fast path only):
//     layer0: A0base (6.3MB) + A0spl (50.3MB)
//     layer1 (overlaid): A1base (12.6MB) + A1spl (100.7MB)
// ---------------------------------------------------------------------------
extern "C" void kernel_launch(void* const* d_in, const int* in_sizes, int n_in,
                              void* d_out, int out_size, void* d_ws,
                              size_t ws_size, hipStream_t stream) {
  const float* x = (const float*)d_in[0];
  const float* terrain = (const float*)d_in[1];
  const float* qkv_w = (const float*)d_in[2];
  const float* qkv_b = (const float*)d_in[3];
  const float* out_w = (const float*)d_in[4];
  const float* out_b = (const float*)d_in[5];
  const float* ln1_s = (const float*)d_in[6];
  const float* ln1_b = (const float*)d_in[7];
  const float* bw0 = (const float*)d_in[8];
  const float* sw0 = (const float*)d_in[9];
  const float* bw1 = (const float*)d_in[10];
  const float* sw1 = (const float*)d_in[11];
  const float* ln2_s = (const float*)d_in[12];
  const float* ln2_b = (const float*)d_in[13];

  float* ws = (float*)d_ws;
  float* qkv = ws;                       // 4096*2304
  float* ao = ws + 9437184;              // 4096*768
  float* attn_out = ws;                  // reuse (qkv dead after attention)
  float* h = ws + 3145728;               // reuse
  float* kan0 = ws + 9437184;            // reuse (ao dead after out-proj)
  float* kan1 = ws + 6291456;            // reuse
  float* outp = (float*)d_out;

  unsigned short* A0base = (unsigned short*)((char*)d_ws + 62914560);
  unsigned short* A0spl = A0base + (size_t)NTOK * EDIM;
  unsigned short* A1base = (unsigned short*)((char*)d_ws + 62914560);
  unsigned short* A1spl = A1base + (size_t)NTOK * D1DIM;
  const bool fast = ws_size >= 176160768ULL;

  // 1. qkv = x @ qkv_w^T + qkv_b
  gemm_mfma_bias<<<dim3(64, 36), 256, 0, stream>>>(x, qkv_w, qkv_b, qkv, EDIM, FDIM);
  // 2. attention -> ao
  attn_mfma<<<dim3(SLEN / 64, NHEAD, BATCH), 256, 0, stream>>>(qkv, ao);
  // 3. attn_out = ao @ out_w^T + out_b
  gemm_mfma_bias<<<dim3(64, 12), 256, 0, stream>>>(ao, out_w, out_b, attn_out, EDIM, EDIM);
  // 4. h = LN(x + attn_out; ln1) * sigmoid(terrain)
  ln_kernel<<<NTOK, 256, 0, stream>>>(x, attn_out, ln1_s, ln1_b, terrain, h);
  if (fast) {
    // 5. precompute silu+bases for layer 0, then GEMM
    kan_prep<<<2048, 256, 0, stream>>>(h, A0base, A0spl, NTOK * EDIM);
    kan_gemm_pre<<<dim3(64, 24), 256, 0, stream>>>(A0base, A0spl, bw0, sw0, kan0,
                                                   EDIM, D1DIM);
    // 6. layer 1
    kan_prep<<<2048, 256, 0, stream>>>(kan0, A1base, A1spl, NTOK * D1DIM);
    kan_gemm_pre<<<dim3(64, 12), 256, 0, stream>>>(A1base, A1spl, bw1, sw1, kan1,
                                                   D1DIM, EDIM);
  } else {
    kan_mfma<<<dim3(64, 24), 256, 0, stream>>>(h, bw0, sw0, kan0, EDIM, D1DIM);
    kan_mfma<<<dim3(64, 12), 256, 0, stream>>>(kan0, bw1, sw1, kan1, D1DIM, EDIM);
  }
  // 7. out = LN(h + kan1; ln2)
  ln_kernel<<<NTOK, 256, 0, stream>>>(h, kan1, ln2_s, ln2_b, nullptr, outp);
}